// Round 1
// 1023.770 us; speedup vs baseline: 1.0330x; 1.0330x over previous
//
#include <hip/hip_runtime.h>
#include <hip/hip_bf16.h>
#include <stdint.h>

// Problem constants: B=2, T=4096, D=4096, H=32, HKV=8, DH=128
#define HS     524288UL        // T*DH (elements)
#define KBASE  33554432UL      // B*H*T*DH
#define VBASE  67108864UL
#define EPSq   1e-5f

typedef unsigned short u16;
typedef unsigned int   u32;
typedef __attribute__((ext_vector_type(8))) __bf16 bf16x8;
typedef __attribute__((ext_vector_type(4))) float  f32x4;

typedef __attribute__((address_space(3))) u32* lds_u32p;
typedef const __attribute__((address_space(1))) u32* g_u32p;

__device__ __forceinline__ void g2lds16(const void* g, void* lds) {
    // per-lane global address, wave-uniform LDS base; HW adds lane*16 on LDS side
    __builtin_amdgcn_global_load_lds((g_u32p)(uintptr_t)g, (lds_u32p)(uintptr_t)lds, 16, 0, 0);
}
__device__ __forceinline__ u16 f2bf(float f) {
    __hip_bfloat16 h = __float2bfloat16(f);   // RNE
    return __builtin_bit_cast(u16, h);
}

// wt row base (in u16 elements over the storage buffer).
// mode 0: contiguous in ws.  mode 1: chunked into batch-0 unused GQA k-slots of
// d_out (heads kv*4+{1,2,3}; 256 rows of 4096 bf16 per 2MB slot; 24 slots).
__device__ __forceinline__ size_t wt_row_off(int n, int mode) {
    if (mode == 0) return (size_t)n * 4096;
    int c = n >> 8;
    int head = (c / 3) * 4 + (c % 3) + 1;
    return 2 * (KBASE + (size_t)head * HS) + (size_t)(n & 255) * 4096;
}

// ---------------------------------------------------------------------------
// Kernel 0: x (fp32) -> xb (bf16)
// ---------------------------------------------------------------------------
__global__ __launch_bounds__(256) void convert_x(const float4* __restrict__ x,
                                                 ushort4* __restrict__ xb) {
    int i = blockIdx.x * 256 + threadIdx.x;
    for (int g = i; g < 8388608; g += gridDim.x * 256) {   // 33,554,432 / 4
        float4 v = x[g];
        ushort4 o;
        o.x = f2bf(v.x); o.y = f2bf(v.y); o.z = f2bf(v.z); o.w = f2bf(v.w);
        xb[g] = o;
    }
}

// ---------------------------------------------------------------------------
// Kernel 1: transpose+convert [Wq|Wk|Wv] (K x N fp32) -> Wt (N x K bf16)
// ---------------------------------------------------------------------------
__global__ __launch_bounds__(256) void transpose_w(
    const float* Wq, const float* Wk, const float* Wv, u16* wt, int mode)
{
    __shared__ u16 tile[64][65];
    const int n0 = blockIdx.x * 64;   // 96 tiles over N=6144
    const int k0 = blockIdx.y * 64;   // 64 tiles over K=4096
    const float* src; int ldn, c0;
    if (n0 < 4096)      { src = Wq; ldn = 4096; c0 = n0; }
    else if (n0 < 5120) { src = Wk; ldn = 1024; c0 = n0 - 4096; }
    else                { src = Wv; ldn = 1024; c0 = n0 - 5120; }
    const int tx = threadIdx.x & 63, ty = threadIdx.x >> 6;
#pragma unroll
    for (int r = 0; r < 16; ++r) {
        int kr = r * 4 + ty;
        tile[tx][kr] = f2bf(src[(size_t)(k0 + kr) * ldn + c0 + tx]);
    }
    __syncthreads();
#pragma unroll
    for (int r = 0; r < 16; ++r) {
        int nr = r * 4 + ty;
        wt[wt_row_off(n0 + nr, mode) + k0 + tx] = tile[nr][tx];
    }
}

// ---------------------------------------------------------------------------
// Kernel 2: C = x @ [Wq|Wk|Wv]  (M=8192, K=4096, N=6144), bf16 MFMA, fp32 out.
// 256x256 tile, BK=64, 8 waves (2Mx4N), 8-phase schedule with counted vmcnt(6),
// raw s_barrier (no full drains), T2 16B-slot XOR swizzle, T5 setprio, T1 XCD
// swizzle. LDS 128 KiB double-buffered (2 bufs x 4 sections x 128x64 bf16).
// Sections: 0=A rows[0,128), 1=A rows[128,256), 2=B rows[0,128), 3=B[128,256).
// ---------------------------------------------------------------------------
#define SBAR()  do { asm volatile("" ::: "memory"); __builtin_amdgcn_s_barrier(); \
                     asm volatile("" ::: "memory"); } while (0)
#define LGKM0() asm volatile("s_waitcnt lgkmcnt(0)" ::: "memory")
#define VMC(n)  asm volatile("s_waitcnt vmcnt(" #n ")" ::: "memory")
#define CFENCE() asm volatile("" ::: "memory")

__global__ __launch_bounds__(512, 2) void gemm_qkv(
    const u16* xb, const u16* wt, float* out, int mode)
{
    __shared__ u16 Lt[2][4][8192];   // [buf][sec][128*64] = 128 KiB

    const int tid  = threadIdx.x;
    const int lane = tid & 63;
    const int wave = tid >> 6;

    // T1: bijective XCD swizzle, 768 blocks (divisible by 8), m-major within XCD
    const int swz = (blockIdx.x & 7) * 96 + (blockIdx.x >> 3);
    const int m0  = (swz & 31) * 256;        // 32 m-tiles
    const int n0  = (swz >> 5) * 256;        // 24 n-tiles

    // ---- staging state ----
    // chunk c = wave*128 + l*64 + lane; row = c>>3, slot = c&7.
    // LDS is written LINEARLY by global_load_lds; the T2 swizzle is applied by
    // permuting the GLOBAL source slot: srcslot = slot ^ (row&7)  (involution).
    const int srow  = wave * 16 + (lane >> 3);          // row for l=0 (l=1: +8)
    const int sslot = (lane & 7) ^ (lane >> 3);         // (row&7) == lane>>3
    const size_t wtb = wt_row_off(n0, mode);            // n0 is 256-aligned
    const u16* p0a = xb + (size_t)(m0 + srow)       * 4096 + sslot * 8;
    const u16* p0b = xb + (size_t)(m0 + srow + 8)   * 4096 + sslot * 8;
    const u16* p1a = xb + (size_t)(m0 + 128 + srow)     * 4096 + sslot * 8;
    const u16* p1b = xb + (size_t)(m0 + 128 + srow + 8) * 4096 + sslot * 8;
    const u16* p2a = wt + wtb + (size_t)(srow)       * 4096 + sslot * 8;
    const u16* p2b = wt + wtb + (size_t)(srow + 8)   * 4096 + sslot * 8;
    const u16* p3a = wt + wtb + (size_t)(128 + srow)     * 4096 + sslot * 8;
    const u16* p3b = wt + wtb + (size_t)(128 + srow + 8) * 4096 + sslot * 8;
    const int dst0 = wave * 1024;    // u16 elems; l=1 adds 512

#define STAGE(buf, sec) do { \
    g2lds16(p##sec##a, &Lt[buf][sec][dst0]);       p##sec##a += 64; \
    g2lds16(p##sec##b, &Lt[buf][sec][dst0 + 512]); p##sec##b += 64; \
} while (0)

    // ---- fragment state ----
    const int wm = wave >> 2, wn = wave & 3;            // 2x4 wave grid
    const int col16 = lane & 15, quad = lane >> 4;
    const int sl0 = (quad ^ (col16 & 7)) * 8;           // swizzled slot, ks=0 (u16)
    const int sl1 = sl0 ^ 32;                           // ks=1 (= slot^4, *8)

    bf16x8 a[2][4];          // [ks][mf2] — one m-quadrant at a time
    bf16x8 bb[2][2][2];      // [nh][ks][nf2] — both n-halves live
    f32x4  acc[8][4];
#pragma unroll
    for (int i = 0; i < 8; ++i)
#pragma unroll
        for (int j = 0; j < 4; ++j) acc[i][j] = (f32x4)0.0f;

#define READ_A(buf, mq) do { \
    _Pragma("unroll") \
    for (int mf2 = 0; mf2 < 4; ++mf2) { \
        const u16* _p = &Lt[buf][wm][((mq) * 64 + mf2 * 16 + col16) * 64]; \
        a[0][mf2] = *(const bf16x8*)(_p + sl0); \
        a[1][mf2] = *(const bf16x8*)(_p + sl1); \
    } \
} while (0)

#define READ_B(buf, nh) do { \
    _Pragma("unroll") \
    for (int nf2 = 0; nf2 < 2; ++nf2) { \
        const u16* _p = &Lt[buf][2 + (wn >> 1)] \
                          [((wn & 1) * 64 + (nh) * 32 + nf2 * 16 + col16) * 64]; \
        bb[nh][0][nf2] = *(const bf16x8*)(_p + sl0); \
        bb[nh][1][nf2] = *(const bf16x8*)(_p + sl1); \
    } \
} while (0)

#define MMA(mq, nh) do { \
    __builtin_amdgcn_s_setprio(1); \
    _Pragma("unroll") \
    for (int mf2 = 0; mf2 < 4; ++mf2) \
    _Pragma("unroll") \
    for (int nf2 = 0; nf2 < 2; ++nf2) { \
        acc[(mq)*4+mf2][(nh)*2+nf2] = __builtin_amdgcn_mfma_f32_16x16x32_bf16( \
            a[0][mf2], bb[nh][0][nf2], acc[(mq)*4+mf2][(nh)*2+nf2], 0, 0, 0); \
        acc[(mq)*4+mf2][(nh)*2+nf2] = __builtin_amdgcn_mfma_f32_16x16x32_bf16( \
            a[1][mf2], bb[nh][1][nf2], acc[(mq)*4+mf2][(nh)*2+nf2], 0, 0, 0); \
    } \
    __builtin_amdgcn_s_setprio(0); \
} while (0)

    // ---- prologue: tile0 -> buf0 (8 loads), tile1 -> buf1 minus A-hi (6) ----
    STAGE(0, 2); STAGE(0, 3); STAGE(0, 0); STAGE(0, 1);
    CFENCE();                                  // pin t0-group before t1-group
    STAGE(1, 2); STAGE(1, 3); STAGE(1, 0);
    VMC(6);                                    // tile0 fully landed
    SBAR();

    // ---- main loop: iter i consumes tiles 2i (buf0) / 2i+1 (buf1),
    //      prefetches 2i+2 -> buf0, 2i+3 -> buf1. Quadrants (mq,nh):
    //      (0,0)(0,1)(1,1)(1,0). vmcnt(6) only at P4/P8 = 3 half-tiles in flight.
    for (int it = 0; it < 31; ++it) {
        // P1: reads A[0:64)+B-lo of buf0; stages A-hi(buf1, t1)
        READ_A(0, 0); READ_B(0, 0); STAGE(1, 1);
        SBAR(); LGKM0(); MMA(0, 0); SBAR();
        // P2: reads B-hi(buf0); stages B-lo(buf0, t2)  [B-lo reads done @P1-end]
        READ_B(0, 1); STAGE(0, 2);
        SBAR(); LGKM0(); MMA(0, 1); SBAR();
        // P3: reads A[64:128)(buf0); stages B-hi(buf0, t2)
        READ_A(0, 1); STAGE(0, 3);
        SBAR(); LGKM0(); MMA(1, 1); SBAR();
        // P4: stages A-lo(buf0, t2); drain tile t1 (8 oldest), keep 6 in flight
        STAGE(0, 0);
        SBAR(); LGKM0(); MMA(1, 0); VMC(6); SBAR();
        // P5: reads A[0:64)+B-lo of buf1; stages A-hi(buf0, t2)
        READ_A(1, 0); READ_B(1, 0); STAGE(0, 1);
        SBAR(); LGKM0(); MMA(0, 0); SBAR();
        // P6: reads B-hi(buf1); stages B-lo(buf1, t3)
        READ_B(1, 1); STAGE(1, 2);
        SBAR(); LGKM0(); MMA(0, 1); SBAR();
        // P7: reads A[64:128)(buf1); stages B-hi(buf1, t3)
        READ_A(1, 1); STAGE(1, 3);
        SBAR(); LGKM0(); MMA(1, 1); SBAR();
        // P8: stages A-lo(buf1, t3); drain tile t2
        STAGE(1, 0);
        SBAR(); LGKM0(); MMA(1, 0); VMC(6); SBAR();
    }

    // ---- tail iteration (tiles 62,63): only P1's A-hi(buf1,63) stage remains
    READ_A(0, 0); READ_B(0, 0); STAGE(1, 1);
    SBAR(); LGKM0(); MMA(0, 0); SBAR();
    READ_B(0, 1);
    SBAR(); LGKM0(); MMA(0, 1); SBAR();
    READ_A(0, 1);
    SBAR(); LGKM0(); MMA(1, 1); SBAR();
    SBAR(); LGKM0(); MMA(1, 0); VMC(0); SBAR();
    READ_A(1, 0); READ_B(1, 0);
    SBAR(); LGKM0(); MMA(0, 0); SBAR();
    READ_B(1, 1);
    SBAR(); LGKM0(); MMA(0, 1); SBAR();
    READ_A(1, 1);
    SBAR(); LGKM0(); MMA(1, 1); SBAR();
    SBAR(); LGKM0(); MMA(1, 0);

#undef STAGE
#undef READ_A
#undef READ_B
#undef MMA

    // ---- epilogue: C/D layout col=lane&15 (+16*nf), row=quad*4+reg (+16*mf).
    // Wave output = 128 rows x 64 cols; 64-col span sits in ONE head.
    const int b_idx = m0 >> 12;
    const int tbase = m0 & 4095;
    const int ng0   = n0 + wn * 64;
    size_t headbase; int nslots = 1;
    if (ng0 < 4096) {
        headbase = (size_t)(b_idx * 32 + (ng0 >> 7)) * HS;
    } else if (ng0 < 5120) {
        headbase = KBASE + (size_t)(b_idx * 32 + ((ng0 - 4096) >> 7) * 4) * HS;
    } else {
        headbase = VBASE + (size_t)(b_idx * 32 + ((ng0 - 5120) >> 7) * 4) * HS;
        nslots = 4;
    }
    const int c0 = (ng0 & 127) + col16;
#pragma unroll
    for (int mf = 0; mf < 8; ++mf) {
#pragma unroll
        for (int r = 0; r < 4; ++r) {
            int mlocal = wm * 128 + mf * 16 + quad * 4 + r;
            size_t rowb = headbase + (size_t)(tbase + mlocal) * 128;
#pragma unroll
            for (int nf = 0; nf < 4; ++nf) {
                float val = acc[mf][nf][r];
                size_t addr = rowb + c0 + nf * 16;
                out[addr] = val;
                if (nslots == 4) {
                    out[addr + HS]     = val;
                    out[addr + 2 * HS] = val;
                    out[addr + 3 * HS] = val;
                }
            }
        }
    }
}

// ---------------------------------------------------------------------------
// Kernel 3: per (b,t): full-row RMSNorm + gamma + RoPE for q (in place) and
// k (expanded to 4 GQA slots). All fp32.
// ---------------------------------------------------------------------------
__global__ __launch_bounds__(256) void finalize_qk(
    float* out, const float* gq, const float* gk)
{
    const int bt = blockIdx.x;
    const int b  = bt >> 12, t = bt & 4095;
    const int tid = threadIdx.x;

    float qv[8][2], kv[2][2];
    float ssq = 0.f, ssk = 0.f;
#pragma unroll
    for (int j = 0; j < 8; ++j) {
        int p = j * 256 + tid;            // pair index 0..2047 (head-major)
        int head = p >> 6, i = p & 63;
        size_t a = (size_t)(b * 32 + head) * HS + (size_t)t * 128 + 2 * i;
        float2 u = *(const float2*)(out + a);
        qv[j][0] = u.x; qv[j][1] = u.y;
        ssq += u.x * u.x + u.y * u.y;
    }
#pragma unroll
    for (int j = 0; j < 2; ++j) {
        int p = j * 256 + tid;            // pair index 0..511
        int hk = p >> 6, i = p & 63;
        size_t a = KBASE + (size_t)(b * 32 + hk * 4) * HS + (size_t)t * 128 + 2 * i;
        float2 u = *(const float2*)(out + a);
        kv[j][0] = u.x; kv[j][1] = u.y;
        ssk += u.x * u.x + u.y * u.y;
    }
#pragma unroll
    for (int off = 32; off; off >>= 1) {
        ssq += __shfl_xor(ssq, off, 64);
        ssk += __shfl_xor(ssk, off, 64);
    }
    __shared__ float red[2][4];
    if ((tid & 63) == 0) { red[0][tid >> 6] = ssq; red[1][tid >> 6] = ssk; }
    __syncthreads();
    const float sq = red[0][0] + red[0][1] + red[0][2] + red[0][3];
    const float sk = red[1][0] + red[1][1] + red[1][2] + red[1][3];
    const float qs = rsqrtf(sq * (1.f / 4096.f) + EPSq);
    const float ks = rsqrtf(sk * (1.f / 1024.f) + EPSq);
    const float tf = (float)t;
    const float LN1E4_64 = 0.14391156831f;   // ln(10000)/64

#pragma unroll
    for (int j = 0; j < 8; ++j) {
        int p = j * 256 + tid;
        int head = p >> 6, i = p & 63;
        float ang = tf * __expf(-(float)i * LN1E4_64);
        float s, c; sincosf(ang, &s, &c);
        float2 g = *(const float2*)(gq + head * 128 + 2 * i);
        float x1 = qv[j][0] * qs * g.x;
        float x2 = qv[j][1] * qs * g.y;
        float2 o; o.x = x1 * c - x2 * s; o.y = x1 * s + x2 * c;
        size_t a = (size_t)(b * 32 + head) * HS + (size_t)t * 128 + 2 * i;
        *(float2*)(out + a) = o;
    }
#pragma unroll
    for (int j = 0; j < 2; ++j) {
        int p = j * 256 + tid;
        int hk = p >> 6, i = p & 63;
        float ang = tf * __expf(-(float)i * LN1E4_64);
        float s, c; sincosf(ang, &s, &c);
        float2 g = *(const float2*)(gk + hk * 128 + 2 * i);
        float x1 = kv[j][0] * ks * g.x;
        float x2 = kv[j][1] * ks * g.y;
        float2 o; o.x = x1 * c - x2 * s; o.y = x1 * s + x2 * c;
        size_t a = KBASE + (size_t)(b * 32 + hk * 4) * HS + (size_t)t * 128 + 2 * i;
        *(float2*)(out + a) = o;
        *(float2*)(out + a + HS) = o;
        *(float2*)(out + a + 2 * HS) = o;
        *(float2*)(out + a + 3 * HS) = o;
    }
}

// ---------------------------------------------------------------------------
// Fallback: fp32 VALU GEMM (used only if ws can't hold xb). Correctness net.
// ---------------------------------------------------------------------------
__global__ __launch_bounds__(256) void gemm_f32(
    const float* x, const float* Wq, const float* Wk, const float* Wv, float* out)
{
    __shared__ float As[16][65], Bs[16][65];
    const int m0 = blockIdx.x * 64;
    const int c0 = blockIdx.y * 64;
    const float* W; int ldn, nc0;
    if (c0 < 4096)      { W = Wq; ldn = 4096; nc0 = c0; }
    else if (c0 < 5120) { W = Wk; ldn = 1024; nc0 = c0 - 4096; }
    else                { W = Wv; ldn = 1024; nc0 = c0 - 5120; }
    const int tid = threadIdx.x, tx = tid & 15, ty = tid >> 4;
    float acc[4][4] = {};
    for (int k0 = 0; k0 < 4096; k0 += 16) {
        __syncthreads();
#pragma unroll
        for (int l = 0; l < 4; ++l) {
            int idx = l * 256 + tid;
            int m = idx >> 4, k = idx & 15;
            As[k][m] = x[(size_t)(m0 + m) * 4096 + k0 + k];
        }
#pragma unroll
        for (int l = 0; l < 4; ++l) {
            int idx = l * 256 + tid;
            int k = idx >> 6, n = idx & 63;
            Bs[k][n] = W[(size_t)(k0 + k) * ldn + nc0 + n];
        }
        __syncthreads();
#pragma unroll
        for (int k = 0; k < 16; ++k) {
            float a[4], bbv[4];
#pragma unroll
            for (int i = 0; i < 4; ++i) { a[i] = As[k][ty * 4 + i]; bbv[i] = Bs[k][tx * 4 + i]; }
#pragma unroll
            for (int i = 0; i < 4; ++i)
#pragma unroll
                for (int j = 0; j < 4; ++j) acc[i][j] += a[i] * bbv[j];
        }
    }
    const int b = m0 >> 12, tbase = m0 & 4095;
#pragma unroll
    for (int i = 0; i < 4; ++i) {
#pragma unroll
        for (int j = 0; j < 4; ++j) {
            int m = ty * 4 + i, c = c0 + tx * 4 + j;
            float v = acc[i][j];
            size_t addr; int ns = 1;
            if (c < 4096) {
                addr = (size_t)(b * 32 + (c >> 7)) * HS + (size_t)(tbase + m) * 128 + (c & 127);
            } else if (c < 5120) {
                addr = KBASE + (size_t)(b * 32 + ((c - 4096) >> 7) * 4) * HS
                     + (size_t)(tbase + m) * 128 + ((c - 4096) & 127);
            } else {
                addr = VBASE + (size_t)(b * 32 + ((c - 5120) >> 7) * 4) * HS
                     + (size_t)(tbase + m) * 128 + ((c - 5120) & 127);
                ns = 4;
            }
            out[addr] = v;
            if (ns == 4) { out[addr + HS] = v; out[addr + 2 * HS] = v; out[addr + 3 * HS] = v; }
        }
    }
}

extern "C" void kernel_launch(void* const* d_in, const int* in_sizes, int n_in,
                              void* d_out, int out_size, void* d_ws, size_t ws_size,
                              hipStream_t stream)
{
    const float* x  = (const float*)d_in[0];
    const float* Wq = (const float*)d_in[1];
    const float* Wk = (const float*)d_in[2];
    const float* Wv = (const float*)d_in[3];
    const float* gq = (const float*)d_in[4];
    const float* gk = (const float*)d_in[5];
    float* out = (float*)d_out;

    const size_t xb_bytes = 8192ULL * 4096ULL * 2ULL;   // 67,108,864
    const size_t wt_bytes = 6144ULL * 4096ULL * 2ULL;   // 50,331,648
    dim3 tb(256);

    if (ws_size >= xb_bytes) {
        u16* xb = (u16*)d_ws;
        u16* wt; int mode;
        if (ws_size >= xb_bytes + wt_bytes) { wt = (u16*)((char*)d_ws + xb_bytes); mode = 0; }
        else                                { wt = (u16*)d_out; mode = 1; }
        convert_x  <<<dim3(2048),    tb, 0, stream>>>((const float4*)x, (ushort4*)xb);
        transpose_w<<<dim3(96, 64),  tb, 0, stream>>>(Wq, Wk, Wv, wt, mode);
        gemm_qkv   <<<dim3(768), dim3(512), 0, stream>>>(xb, wt, out, mode);
    } else {
        gemm_f32   <<<dim3(128, 96), tb, 0, stream>>>(x, Wq, Wk, Wv, out);
    }
    finalize_qk<<<dim3(8192), tb, 0, stream>>>(out, gq, gk);
}